// Round 11
// baseline (371.519 us; speedup 1.0000x reference)
//
#include <hip/hip_runtime.h>
#include <stdint.h>

#define NEUR 1024
#define BM 128            // rows per block
#define THREADS 512
#define H1S 528           // h1 quarter row stride bytes (256 bf16 + 16B pad, 16B-aligned)
#define L1S 80            // l1p row stride bytes

typedef short  s16x8  __attribute__((ext_vector_type(8)));
typedef __bf16 bf16x8 __attribute__((ext_vector_type(8)));
typedef float  f32x16 __attribute__((ext_vector_type(16)));

__device__ __forceinline__ unsigned short f2bf(float f){
  unsigned u = __builtin_bit_cast(unsigned, f);
  u += 0x7FFFu + ((u >> 16) & 1u);          // round-to-nearest-even
  return (unsigned short)(u >> 16);
}
__device__ __forceinline__ float bf2f(unsigned short h){
  unsigned u = ((unsigned)h) << 16;
  return __builtin_bit_cast(float, u);
}
__device__ __forceinline__ f32x16 mfma32(bf16x8 a, bf16x8 b, f32x16 c){
  return __builtin_amdgcn_mfma_f32_32x32x16_bf16(a, b, c, 0, 0, 0);
}
__device__ __forceinline__ f32x16 zero16(){
  f32x16 v;
#pragma unroll
  for (int r = 0; r < 16; ++r) v[r] = 0.f;
  return v;
}
__device__ __forceinline__ bf16x8 ld16(const void* p){
  return __builtin_bit_cast(bf16x8, *reinterpret_cast<const s16x8*>(p));
}
// async global->LDS, 16B per lane; LDS dest = uniform base + lane*16
__device__ __forceinline__ void gll16(const void* gsrc, void* ldst){
  __builtin_amdgcn_global_load_lds(
      (const __attribute__((address_space(1))) unsigned int*)gsrc,
      (__attribute__((address_space(3))) unsigned int*)ldst, 16, 0, 0);
}

// Pre-swizzle weights into MFMA-fragment order (coalesced GEMM loads).
// w2opt[((nt*64 + ks)*64 + l)*8 + j] = bf16(W2[nt*32 + (l&31)][ks*16 + (l>>5)*8 + j])
// w1opt[((nt*2  + ks)*64 + l)*8 + j] = bf16(W1 padded to K=32, same fragment map)
__global__ void prep_kernel(const float* __restrict__ W1, const float* __restrict__ W2,
                            unsigned short* __restrict__ w2opt, unsigned short* __restrict__ w1opt){
  const int nchunks = NEUR * 128;
  const int total = nchunks + 4096;
  for (int i = blockIdx.x*blockDim.x + threadIdx.x; i < total; i += gridDim.x*blockDim.x){
    if (i < nchunks){
      const int col = i >> 7, c8 = i & 127;
      const float* src = W2 + (size_t)col*NEUR + c8*8;
      const int ks = c8 >> 1, lf = c8 & 1, lane = lf*32 + (col & 31), nt = col >> 5;
      unsigned short* dst = w2opt + (((size_t)(nt*64 + ks)*64 + lane) * 8);
#pragma unroll
      for (int j = 0; j < 8; ++j) dst[j] = f2bf(src[j]);
    } else {
      const int o = i - nchunks;
      const int nt = o >> 7, ks = (o >> 6) & 1, lane = o & 63;
      const int col = nt*32 + (lane & 31);
      unsigned short* dst = w1opt + (size_t)o * 8;
#pragma unroll
      for (int j = 0; j < 8; ++j){
        const int k = ks*16 + (lane >> 5)*8 + j;
        dst[j] = (k < 10) ? f2bf(W1[col*10 + k]) : (unsigned short)0;
      }
    }
  }
}

// finish: out = sigmoid(partial[0] + partial[1] + b3)
__global__ void finish_kernel(const float* __restrict__ pws, const float* __restrict__ b3,
                              float* __restrict__ out, int batch){
  const int total = batch * 3;
  for (int i = blockIdx.x*blockDim.x + threadIdx.x; i < total; i += gridDim.x*blockDim.x){
    const int j = i - (i/3)*3;
    const float v = pws[i] + pws[(size_t)total + i] + b3[j];
    out[i] = 1.f / (1.f + __expf(-v));
  }
}

// Main fused kernel: BM=128 x 512 cols per block; K split into 4 quarters of 256;
// W2 fragments staged in LDS (global_load_lds, double-buffered 32K-chunks) shared
// by all 8 waves -> per-CU L2 traffic halved vs private register loads.
__global__ __launch_bounds__(THREADS, 2) void mlp_kernel(
    const float* __restrict__ x,
    const float* __restrict__ Wx, const float* __restrict__ bxp,
    const float* __restrict__ Wu, const float* __restrict__ bup,
    const float* __restrict__ b1, const float* __restrict__ b2,
    const float* __restrict__ W3,
    const unsigned short* __restrict__ w2opt, const unsigned short* __restrict__ w1opt,
    float* __restrict__ pws, int batch)
{
  extern __shared__ char smem[];
  char* l1p = smem;                       // [128][L1S]  10240 B (reused as sp in epilogue)
  char* h1  = smem + BM*L1S;              // [128][H1S]  67584 B (current K-quarter of h1)
  char* bb0 = h1 + BM*H1S;                // 32768 B  B-chunk buffer 0
  char* bb1 = bb0 + 32768;                // 32768 B  B-chunk buffer 1   (total 143360)

  const int tid = threadIdx.x;
  const int l   = tid & 63;
  const int wid = tid >> 6;               // 8 waves
  const int l31 = l & 31;
  const int lh  = l >> 5;
  const int wm  = wid >> 2;               // 0..1 rows half
  const int wn  = wid & 3;                // 0..3 col quarter (128 cols each)
  const int bm  = blockIdx.x >> 1;
  const int bn  = blockIdx.x & 1;
  const long rbase = (long)bm * BM;

  // ---- 1. stage x tile (128*25 f32) into h1 region
  float* xs = (float*)h1;
  for (int i = tid; i < BM*25; i += THREADS) xs[i] = x[rbase*25 + i];
  __syncthreads();

  // ---- 2. l1 features (f32 exact), bf16-pad to K=32
  if (tid < BM){
    const float* xr = xs + tid*25;
    float l1v[10];
#pragma unroll
    for (int g = 0; g < 3; ++g)
#pragma unroll
      for (int o = 0; o < 2; ++o){
        float s = bxp[o];
#pragma unroll
        for (int i = 0; i < 5; ++i) s += xr[g + 3*i] * Wx[o*5 + i];
        l1v[g*2 + o] = fmaxf(s, 0.f);
      }
#pragma unroll
    for (int g = 0; g < 2; ++g)
#pragma unroll
      for (int o = 0; o < 2; ++o){
        float s = bup[o];
#pragma unroll
        for (int i = 0; i < 5; ++i) s += xr[15 + g + 2*i] * Wu[o*5 + i];
        l1v[6 + g*2 + o] = fmaxf(s, 0.f);
      }
    unsigned short* dst = (unsigned short*)(l1p + tid*L1S);
#pragma unroll
    for (int i = 0; i < 10; ++i) dst[i] = f2bf(l1v[i]);
#pragma unroll
    for (int i = 10; i < 32; ++i) dst[i] = 0;
  }
  __syncthreads();

  // ---- persistent GEMM2 accumulators: wave tile 64 rows x 128 cols
  f32x16 acc[2][4];
#pragma unroll
  for (int mt = 0; mt < 2; ++mt)
#pragma unroll
    for (int nt = 0; nt < 4; ++nt) acc[mt][nt] = zero16();

  const int a0off = (wm*64 + l31)*H1S + lh*16;       // A frag base in h1
  const int a1off = a0off + 32*H1S;
  const int bro0  = ((wn*4 + 0)*2)*1024 + l*16;      // B frag bases in chunk buffer
  const int bro1  = ((wn*4 + 1)*2)*1024 + l*16;
  const int bro2  = ((wn*4 + 2)*2)*1024 + l*16;
  const int bro3  = ((wn*4 + 3)*2)*1024 + l*16;

  // chunk g covers global ks {2g, 2g+1}; wave stages its 2 n-tiles (4 x gll16)
#define STAGE(G, DST) do{                                                         \
    const char* s_ = (const char*)w2opt +                                         \
        (((size_t)(bn*16 + wid*2)*64 + 2*(G))*64 + l)*16;                         \
    char* d_ = (DST) + wid*4096;                                                  \
    gll16(s_,                 d_);                                                \
    gll16(s_ + 1024,          d_ + 1024);                                         \
    gll16(s_ + 65536,         d_ + 2048);                                         \
    gll16(s_ + 65536 + 1024,  d_ + 3072);                                         \
  }while(0)

#define CHUNK(C, CUR, DO_STAGE, NXT, GNEXT) do{                                   \
    if (DO_STAGE) STAGE(GNEXT, NXT);                                              \
    _Pragma("unroll")                                                             \
    for (int ksl = 0; ksl < 2; ++ksl){                                            \
      const int kq_ = (C)*2 + ksl;                                                \
      bf16x8 A0 = ld16(h1 + a0off + kq_*32);                                      \
      bf16x8 A1 = ld16(h1 + a1off + kq_*32);                                      \
      bf16x8 B0 = ld16((CUR) + bro0 + ksl*1024);                                  \
      bf16x8 B1 = ld16((CUR) + bro1 + ksl*1024);                                  \
      bf16x8 B2 = ld16((CUR) + bro2 + ksl*1024);                                  \
      bf16x8 B3 = ld16((CUR) + bro3 + ksl*1024);                                  \
      __builtin_amdgcn_s_setprio(1);                                              \
      acc[0][0]=mfma32(A0,B0,acc[0][0]); acc[1][0]=mfma32(A1,B0,acc[1][0]);       \
      acc[0][1]=mfma32(A0,B1,acc[0][1]); acc[1][1]=mfma32(A1,B1,acc[1][1]);       \
      acc[0][2]=mfma32(A0,B2,acc[0][2]); acc[1][2]=mfma32(A1,B2,acc[1][2]);       \
      acc[0][3]=mfma32(A0,B3,acc[0][3]); acc[1][3]=mfma32(A1,B3,acc[1][3]);       \
      __builtin_amdgcn_s_setprio(0);                                              \
    }                                                                             \
    __syncthreads();                                                              \
  }while(0)

  STAGE(0, bb0);                          // prologue: chunk 0 in flight

  for (int q = 0; q < 4; ++q){
    // ---- GEMM1 quarter q: h1[128][256] = relu(l1 @ W1[q*256..+256]^T + b1)
    {
      f32x16 c00 = zero16(), c01 = zero16(), c10 = zero16(), c11 = zero16();
#pragma unroll
      for (int ks = 0; ks < 2; ++ks){
        bf16x8 a0 = ld16(l1p + (wm*64 + l31)*L1S + ks*32 + lh*16);
        bf16x8 a1 = ld16(l1p + (wm*64 + 32 + l31)*L1S + ks*32 + lh*16);
        const int ntg = q*8 + wn*2;
        bf16x8 b0 = ld16(w1opt + (((size_t)(ntg + 0)*2 + ks)*64 + l)*8);
        bf16x8 b1f= ld16(w1opt + (((size_t)(ntg + 1)*2 + ks)*64 + l)*8);
        c00 = mfma32(a0, b0, c00);
        c10 = mfma32(a1, b0, c10);
        c01 = mfma32(a0, b1f, c01);
        c11 = mfma32(a1, b1f, c11);
      }
#pragma unroll
      for (int nt2 = 0; nt2 < 2; ++nt2){
        const int colq = wn*64 + nt2*32 + l31;
        const float bv = b1[q*256 + colq];
        const f32x16& cA = nt2 ? c01 : c00;
        const f32x16& cB = nt2 ? c11 : c10;
#pragma unroll
        for (int r = 0; r < 16; ++r){
          const int rr = (r & 3) + 8*(r >> 2) + 4*lh;
          *(unsigned short*)(h1 + (wm*64 + rr)*H1S + colq*2)      = f2bf(fmaxf(cA[r] + bv, 0.f));
          *(unsigned short*)(h1 + (wm*64 + 32 + rr)*H1S + colq*2) = f2bf(fmaxf(cB[r] + bv, 0.f));
        }
      }
    }
    __syncthreads();

    // ---- GEMM2 quarter: 8 chunks, 2-phase double-buffer (buf parity = chunk parity)
    const int g0 = q*8;
    CHUNK(0, bb0, true,   bb1, g0 + 1);
    CHUNK(1, bb1, true,   bb0, g0 + 2);
    CHUNK(2, bb0, true,   bb1, g0 + 3);
    CHUNK(3, bb1, true,   bb0, g0 + 4);
    CHUNK(4, bb0, true,   bb1, g0 + 5);
    CHUNK(5, bb1, true,   bb0, g0 + 6);
    CHUNK(6, bb0, true,   bb1, g0 + 7);
    CHUNK(7, bb1, (q < 3), bb0, g0 + 8);
  }
#undef STAGE
#undef CHUNK

  // ---- epilogue: h2 = relu(acc + b2); per-wave partial logits; lane-reduce;
  //      stage in LDS sp[wn][128][3]; cross-wn sum -> pws[bn]. (R10, verified)
  float* sp = (float*)l1p;
  {
    float b2v[4], w30[4], w31[4], w32[4];
#pragma unroll
    for (int nt = 0; nt < 4; ++nt){
      const int colg = bn*512 + wn*128 + nt*32 + l31;
      b2v[nt] = b2[colg];
      w30[nt] = W3[0*NEUR + colg];
      w31[nt] = W3[1*NEUR + colg];
      w32[nt] = W3[2*NEUR + colg];
    }
#pragma unroll
    for (int mf = 0; mf < 2; ++mf){
      float p0[16], p1[16], p2[16];
#pragma unroll
      for (int r = 0; r < 16; ++r){ p0[r] = 0.f; p1[r] = 0.f; p2[r] = 0.f; }
#pragma unroll
      for (int nt = 0; nt < 4; ++nt)
#pragma unroll
        for (int r = 0; r < 16; ++r){
          const float hv = fmaxf(acc[mf][nt][r] + b2v[nt], 0.f);
          p0[r] += hv * w30[nt];
          p1[r] += hv * w31[nt];
          p2[r] += hv * w32[nt];
        }
#pragma unroll
      for (int off = 1; off < 32; off <<= 1)
#pragma unroll
        for (int r = 0; r < 16; ++r){
          p0[r] += __shfl_xor(p0[r], off, 64);
          p1[r] += __shfl_xor(p1[r], off, 64);
          p2[r] += __shfl_xor(p2[r], off, 64);
        }
      if (l31 == 0){
#pragma unroll
        for (int r = 0; r < 16; ++r){
          const int row = wm*64 + mf*32 + (r & 3) + 8*(r >> 2) + 4*lh;
          float* d = sp + ((size_t)wn*BM + row)*3;
          d[0] = p0[r]; d[1] = p1[r]; d[2] = p2[r];
        }
      }
    }
  }
  __syncthreads();

  for (int t2 = tid; t2 < BM*3; t2 += THREADS){
    const int row = t2 / 3, j = t2 - row*3;
    const float v = sp[(0*BM + row)*3 + j] + sp[(1*BM + row)*3 + j]
                  + sp[(2*BM + row)*3 + j] + sp[(3*BM + row)*3 + j];
    pws[((size_t)bn*batch + rbase + row)*3 + j] = v;
  }
}

// ---------- fallback (ws too small): round-8 kernel, direct W2 reads ----------
__global__ __launch_bounds__(THREADS, 2) void mlp_kernel_old(
    const float* __restrict__ x,
    const float* __restrict__ Wx, const float* __restrict__ bxp,
    const float* __restrict__ Wu, const float* __restrict__ bup,
    const float* __restrict__ W1, const float* __restrict__ b1,
    const float* __restrict__ W2f, const float* __restrict__ b2,
    const float* __restrict__ W3, const float* __restrict__ b3,
    float* __restrict__ out)
{
  extern __shared__ char smem[];
  unsigned short* l1p = (unsigned short*)smem;
  char* h1 = smem + 5120;   // 64 x 2064
  const int tid = threadIdx.x, l = tid & 63, wid = tid >> 6;
  const int l31 = l & 31, lh = l >> 5;
  const long rbase = (long)blockIdx.x * 64;

  float* xs = (float*)h1;
  for (int i = tid; i < 64*25; i += THREADS) xs[i] = x[rbase*25 + i];
  __syncthreads();
  if (tid < 64){
    const float* xr = xs + tid*25;
    float l1v[10];
#pragma unroll
    for (int g = 0; g < 3; ++g)
#pragma unroll
      for (int o = 0; o < 2; ++o){
        float s = bxp[o];
#pragma unroll
        for (int i = 0; i < 5; ++i) s += xr[g + 3*i] * Wx[o*5 + i];
        l1v[g*2 + o] = fmaxf(s, 0.f);
      }
#pragma unroll
    for (int g = 0; g < 2; ++g)
#pragma unroll
      for (int o = 0; o < 2; ++o){
        float s = bup[o];
#pragma unroll
        for (int i = 0; i < 5; ++i) s += xr[15 + g + 2*i] * Wu[o*5 + i];
        l1v[6 + g*2 + o] = fmaxf(s, 0.f);
      }
    unsigned short* dst = l1p + tid*40;
#pragma unroll
    for (int i = 0; i < 10; ++i) dst[i] = f2bf(l1v[i]);
#pragma unroll
    for (int i = 10; i < 32; ++i) dst[i] = 0;
  }
  __syncthreads();

  f32x16 c[2][4];
#pragma unroll
  for (int mt = 0; mt < 2; ++mt)
#pragma unroll
    for (int nt = 0; nt < 4; ++nt) c[mt][nt] = zero16();
#pragma unroll
  for (int ks = 0; ks < 2; ++ks){
    bf16x8 a0 = ld16(smem + l31*80 + ks*32 + lh*16);
    bf16x8 a1 = ld16(smem + (32 + l31)*80 + ks*32 + lh*16);
#pragma unroll
    for (int nt = 0; nt < 4; ++nt){
      const int col = wid*128 + nt*32 + l31;
      s16x8 raw;
#pragma unroll
      for (int j = 0; j < 8; ++j){
        const int k = ks*16 + lh*8 + j;
        raw[j] = (k < 10) ? (short)f2bf(W1[col*10 + k]) : (short)0;
      }
      bf16x8 b = __builtin_bit_cast(bf16x8, raw);
      c[0][nt] = mfma32(a0, b, c[0][nt]);
      c[1][nt] = mfma32(a1, b, c[1][nt]);
    }
  }
#pragma unroll
  for (int nt = 0; nt < 4; ++nt){
    const int col = wid*128 + nt*32 + l31;
    const float bv = b1[col];
#pragma unroll
    for (int mt = 0; mt < 2; ++mt)
#pragma unroll
      for (int r = 0; r < 16; ++r){
        const int row = mt*32 + (r & 3) + 8*(r >> 2) + 4*lh;
        *reinterpret_cast<unsigned short*>(h1 + row*2064 + col*2) =
            f2bf(fmaxf(c[mt][nt][r] + bv, 0.f));
      }
  }
  __syncthreads();

  f32x16 acc[2][4];
#pragma unroll
  for (int mt = 0; mt < 2; ++mt)
#pragma unroll
    for (int nt = 0; nt < 4; ++nt) acc[mt][nt] = zero16();
  const int aA0 = l31*2064 + lh*16;
  for (int ks = 0; ks < 64; ++ks){
    bf16x8 A0 = ld16(h1 + aA0 + ks*32);
    bf16x8 A1 = ld16(h1 + aA0 + 32*2064 + ks*32);
#pragma unroll
    for (int nt = 0; nt < 4; ++nt){
      const int col = wid*128 + nt*32 + l31;
      const float* p = W2f + (size_t)col*NEUR + ks*16 + lh*8;
      s16x8 raw;
#pragma unroll
      for (int j = 0; j < 8; ++j) raw[j] = (short)f2bf(p[j]);
      bf16x8 B = __builtin_bit_cast(bf16x8, raw);
      acc[0][nt] = mfma32(A0, B, acc[0][nt]);
      acc[1][nt] = mfma32(A1, B, acc[1][nt]);
    }
  }
  __syncthreads();
#pragma unroll
  for (int nt = 0; nt < 4; ++nt){
    const int col = wid*128 + nt*32 + l31;
    const float bv = b2[col];
#pragma unroll
    for (int mt = 0; mt < 2; ++mt)
#pragma unroll
      for (int r = 0; r < 16; ++r){
        const int row = mt*32 + (r & 3) + 8*(r >> 2) + 4*lh;
        *reinterpret_cast<unsigned short*>(h1 + row*2064 + col*2) =
            f2bf(fmaxf(acc[mt][nt][r] + bv, 0.f));
      }
  }
  __syncthreads();
  float s[8][3];
#pragma unroll
  for (int rr = 0; rr < 8; ++rr)
#pragma unroll
    for (int j = 0; j < 3; ++j) s[rr][j] = 0.f;
#pragma unroll
  for (int h = 0; h < 2; ++h){
    const int k0 = h*512 + l*8;
    float w3v[3][8];
#pragma unroll
    for (int j = 0; j < 3; ++j)
#pragma unroll
      for (int i = 0; i < 8; ++i) w3v[j][i] = W3[j*NEUR + k0 + i];
#pragma unroll
    for (int rr = 0; rr < 8; ++rr){
      const int row = wid*8 + rr;
      s16x8 raw = *reinterpret_cast<const s16x8*>(h1 + row*2064 + k0*2);
#pragma unroll
      for (int i = 0; i < 8; ++i){
        const float hv = bf2f((unsigned short)raw[i]);
        s[rr][0] += hv * w3v[0][i];
        s[rr][1] += hv * w3v[1][i];
        s[rr][2] += hv * w3v[2][i];
      }
    }
  }
#pragma unroll
  for (int off = 1; off < 64; off <<= 1)
#pragma unroll
    for (int rr = 0; rr < 8; ++rr)
#pragma unroll
      for (int j = 0; j < 3; ++j) s[rr][j] += __shfl_xor(s[rr][j], off, 64);
  if (l == 0){
#pragma unroll
    for (int rr = 0; rr < 8; ++rr){
      const int row = wid*8 + rr;
#pragma unroll
      for (int j = 0; j < 3; ++j)
        out[(rbase + row)*3 + j] = 1.f / (1.f + __expf(-(s[rr][j] + b3[j])));
    }
  }
}

extern "C" void kernel_launch(void* const* d_in, const int* in_sizes, int n_in,
                              void* d_out, int out_size, void* d_ws, size_t ws_size,
                              hipStream_t stream){
  const float* x  = (const float*)d_in[0];
  const float* Wx = (const float*)d_in[1];
  const float* bx = (const float*)d_in[2];
  const float* Wu = (const float*)d_in[3];
  const float* bu = (const float*)d_in[4];
  const float* W1 = (const float*)d_in[5];
  const float* b1 = (const float*)d_in[6];
  const float* W2 = (const float*)d_in[7];
  const float* b2 = (const float*)d_in[8];
  const float* W3 = (const float*)d_in[9];
  const float* b3 = (const float*)d_in[10];
  float* out = (float*)d_out;

  const int batch = in_sizes[0] / 25;
  const size_t w2_bytes  = (size_t)NEUR*NEUR*2;          // 2 MB
  const size_t w1_bytes  = (size_t)4096*8*2;             // 64 KB
  const size_t pws_bytes = (size_t)batch*3*2*4;          // 3.1 MB
  const size_t ws_need   = w2_bytes + w1_bytes + pws_bytes;

  if (ws_size >= ws_need && (batch % BM) == 0){
    unsigned short* w2opt = (unsigned short*)d_ws;
    unsigned short* w1opt = (unsigned short*)((char*)d_ws + w2_bytes);
    float* pws            = (float*)((char*)d_ws + w2_bytes + w1_bytes);

    prep_kernel<<<512, 256, 0, stream>>>(W1, W2, w2opt, w1opt);

    const int smem = BM*L1S + BM*H1S + 2*32768;   // 10240+67584+65536 = 143360 B
    hipFuncSetAttribute(reinterpret_cast<const void*>(mlp_kernel),
                        hipFuncAttributeMaxDynamicSharedMemorySize, smem);
    const int nblocks = (batch / BM) * 2;
    mlp_kernel<<<nblocks, THREADS, smem, stream>>>(
        x, Wx, bx, Wu, bu, b1, b2, W3, w2opt, w1opt, pws, batch);

    finish_kernel<<<(batch*3 + 255)/256, 256, 0, stream>>>(pws, b3, out, batch);
  } else {
    const int smem = 5120 + 64*2064;
    hipFuncSetAttribute(reinterpret_cast<const void*>(mlp_kernel_old),
                        hipFuncAttributeMaxDynamicSharedMemorySize, smem);
    mlp_kernel_old<<<batch/64, THREADS, smem, stream>>>(
        x, Wx, bx, Wu, bu, W1, b1, W2, b2, W3, b3, out);
  }
}